// Round 4
// baseline (4169.669 us; speedup 1.0000x reference)
//
#include <hip/hip_runtime.h>
#include <hip/hip_bf16.h>
#include <math.h>

#define NPTS 2048
#define NB 16
#define KNN 20
#define GP 40   // LDS pitch in bf16 elements for 32-k staging buffers

typedef __attribute__((ext_vector_type(8))) short bf16x8;
typedef __attribute__((ext_vector_type(4))) float f32x4;

__device__ __forceinline__ float lrelu(float v) { return fmaxf(v, 0.2f * v); }

// split two floats into packed bf16 hi pair + packed bf16 lo (residual) pair
__device__ __forceinline__ void split2(float a, float b, unsigned& hp, unsigned& lp) {
    float2 f2; f2.x = a; f2.y = b;
    __hip_bfloat162 h2 = __float22bfloat162_rn(f2);
    unsigned hb; __builtin_memcpy(&hb, &h2, 4);
    float la = a - __uint_as_float(hb << 16);
    float lb = b - __uint_as_float(hb & 0xFFFF0000u);
    float2 l2; l2.x = la; l2.y = lb;
    __hip_bfloat162 k2 = __float22bfloat162_rn(l2);
    unsigned lb2; __builtin_memcpy(&lb2, &k2, 4);
    hp = hb; lp = lb2;
}

// ---- transpose x [B,N,3] -> h0 [B,3,N]
__global__ void transpose_kernel(const float* __restrict__ x, float* __restrict__ h0) {
    int t = blockIdx.x * blockDim.x + threadIdx.x;
    if (t >= NB * NPTS) return;
    int b = t / NPTS, n = t % NPTS;
    const float* src = x + (size_t)t * 3;
    float* dst = h0 + (size_t)b * 3 * NPTS + n;
    dst[0]        = src[0];
    dst[NPTS]     = src[1];
    dst[2 * NPTS] = src[2];
}

// ---- split layer input [b][c][m] fp32 -> xh/xl [b][m][CP] bf16 (transposed), + sq
__global__ __launch_bounds__(256) void xsplit_kernel(const float* __restrict__ in, long bstride,
                                                     int C, int CP,
                                                     unsigned short* __restrict__ xh,
                                                     unsigned short* __restrict__ xl,
                                                     float* __restrict__ sq) {
    int t = blockIdx.x * 256 + threadIdx.x;      // b*N + m
    int b = t >> 11;
    int m = t & 2047;
    const float* p = in + (size_t)b * bstride + m;
    unsigned short* ph = xh + (size_t)t * CP;
    unsigned short* pl = xl + (size_t)t * CP;
    float s = 0.f;
    for (int c0 = 0; c0 < CP; c0 += 8) {
        float v[8];
        unsigned hw[4], lw[4];
#pragma unroll
        for (int j = 0; j < 8; ++j) {
            int c = c0 + j;
            v[j] = (c < C) ? p[(size_t)c * NPTS] : 0.f;
            s = fmaf(v[j], v[j], s);
        }
#pragma unroll
        for (int pp = 0; pp < 4; ++pp) split2(v[2 * pp], v[2 * pp + 1], hw[pp], lw[pp]);
        *(uint4*)(ph + c0) = make_uint4(hw[0], hw[1], hw[2], hw[3]);
        *(uint4*)(pl + c0) = make_uint4(lw[0], lw[1], lw[2], lw[3]);
    }
    sq[t] = s;
}

// ---- fused kNN: per block, 16 query rows x all 2048 m.
// MFMA (bf16 hi/lo 3-pass) fills scores[16][2050] in LDS chunk-by-chunk,
// then wave-per-row register top-20 (proven round-1 logic).
template<int CP>
__global__ __launch_bounds__(256) void knn_fused(const unsigned short* __restrict__ xh,
                                                 const unsigned short* __restrict__ xl,
                                                 const float* __restrict__ sq,
                                                 int* __restrict__ idx) {
    extern __shared__ __align__(16) char smem[];
    constexpr int AP = CP + 8;
    unsigned short* Ah = (unsigned short*)smem;
    unsigned short* Al = Ah + 16 * AP;
    unsigned short* Bh = Al + 16 * AP;
    unsigned short* Bl = Bh + 128 * GP;
    float* scores = (float*)(Bl + 128 * GP);

    int nt = blockIdx.x, b = blockIdx.y;
    int n0 = nt * 16;
    int tid = threadIdx.x;
    int lane = tid & 63, w = tid >> 6;
    int l15 = lane & 15, q = lane >> 4;
    const unsigned short* xhb = xh + (size_t)b * NPTS * CP;
    const unsigned short* xlb = xl + (size_t)b * NPTS * CP;

    // stage A (16 query rows, all K) once
    for (int e = tid; e < 16 * (CP / 8); e += 256) {
        int r = e / (CP / 8), kb = e % (CP / 8);
        *(uint4*)&Ah[r * AP + kb * 8] = *(const uint4*)&xhb[(size_t)(n0 + r) * CP + kb * 8];
        *(uint4*)&Al[r * AP + kb * 8] = *(const uint4*)&xlb[(size_t)(n0 + r) * CP + kb * 8];
    }

    int bn = tid & 127, kh = tid >> 7;

    for (int ch = 0; ch < 16; ++ch) {
        int m0 = ch * 128;
        f32x4 acc[2];
        acc[0] = (f32x4)0.f; acc[1] = (f32x4)0.f;
#pragma unroll
        for (int ks = 0; ks < CP / 32; ++ks) {
            __syncthreads();   // protect prior frag reads (and A-stage on first pass)
            {
                const unsigned short* sh = xhb + (size_t)(m0 + bn) * CP + ks * 32 + kh * 16;
                const unsigned short* sl = xlb + (size_t)(m0 + bn) * CP + ks * 32 + kh * 16;
                *(uint4*)&Bh[bn * GP + kh * 16]     = *(const uint4*)(sh);
                *(uint4*)&Bh[bn * GP + kh * 16 + 8] = *(const uint4*)(sh + 8);
                *(uint4*)&Bl[bn * GP + kh * 16]     = *(const uint4*)(sl);
                *(uint4*)&Bl[bn * GP + kh * 16 + 8] = *(const uint4*)(sl + 8);
            }
            __syncthreads();
            bf16x8 ah = *(const bf16x8*)&Ah[l15 * AP + ks * 32 + q * 8];
            bf16x8 al = *(const bf16x8*)&Al[l15 * AP + ks * 32 + q * 8];
#pragma unroll
            for (int ni = 0; ni < 2; ++ni) {
                int row = w * 32 + ni * 16 + l15;
                bf16x8 bh = *(const bf16x8*)&Bh[row * GP + q * 8];
                bf16x8 bl = *(const bf16x8*)&Bl[row * GP + q * 8];
                acc[ni] = __builtin_amdgcn_mfma_f32_16x16x32_bf16(ah, bh, acc[ni], 0, 0, 0);
                acc[ni] = __builtin_amdgcn_mfma_f32_16x16x32_bf16(ah, bl, acc[ni], 0, 0, 0);
                acc[ni] = __builtin_amdgcn_mfma_f32_16x16x32_bf16(al, bh, acc[ni], 0, 0, 0);
            }
        }
        // epilogue: scores[qrow][m] = 2*inner - sq[m]
#pragma unroll
        for (int ni = 0; ni < 2; ++ni) {
            int mcol = m0 + w * 32 + ni * 16 + l15;
            float sv = sq[b * NPTS + mcol];
#pragma unroll
            for (int r = 0; r < 4; ++r)
                scores[(q * 4 + r) * 2050 + mcol] = 2.f * acc[ni][r] - sv;
        }
    }
    __syncthreads();

    // select: wave w owns rows 4w..4w+3; 32 vals/lane, 20 shuffle-argmax rounds
    for (int rr = 0; rr < 4; ++rr) {
        int row = w * 4 + rr;
        float v[32];
#pragma unroll
        for (int u = 0; u < 32; ++u) v[u] = scores[row * 2050 + lane + 64 * u];
        int* out = idx + ((size_t)b * NPTS + n0 + row) * KNN;

        float lv = v[0]; int lm = 0;
#pragma unroll
        for (int u = 1; u < 32; ++u) { if (v[u] > lv) { lv = v[u]; lm = u; } }

        for (int j = 0; j < KNN; ++j) {
            float bv = lv; int bm = lane + 64 * lm;
#pragma unroll
            for (int off = 32; off > 0; off >>= 1) {
                float ov = __shfl_down(bv, off, 64);
                int   om = __shfl_down(bm, off, 64);
                if (ov > bv || (ov == bv && om < bm)) { bv = ov; bm = om; }
            }
            bm = __shfl(bm, 0, 64);
            if (lane == 0) out[j] = bm;
            if ((bm & 63) == lane) {
                int u = bm >> 6;
#pragma unroll
                for (int qq = 0; qq < 32; ++qq) if (qq == u) v[qq] = -INFINITY;
                lv = v[0]; lm = 0;
#pragma unroll
                for (int qq = 1; qq < 32; ++qq) { if (v[qq] > lv) { lv = v[qq]; lm = qq; } }
            }
        }
    }
}

// ---- Wa[c][o] = W[o][c]; Wd[c][o] = W[o][C+c] - W[o][c]
__global__ void prep_w_kernel(const float* __restrict__ W, int C, int O,
                              float* __restrict__ Wa, float* __restrict__ Wd) {
    int t = blockIdx.x * blockDim.x + threadIdx.x;
    if (t >= C * O) return;
    int c = t / O, o = t % O;
    float a = W[o * 2 * C + c];
    float d = W[o * 2 * C + C + c] - a;
    Wa[c * O + o] = a;
    Wd[c * O + o] = d;
}

// ---- y[b,o,m] = Wa@x_m ; base[b,off+o,n] = Wd@x_n + bias
__global__ __launch_bounds__(256) void edge_mm_kernel(const float* __restrict__ xin, long bstride,
                                                      int C, int O,
                                                      const float* __restrict__ Wa,
                                                      const float* __restrict__ Wd,
                                                      const float* __restrict__ bias,
                                                      float* __restrict__ y,
                                                      float* __restrict__ base, long base_bstride) {
    int m = blockIdx.x * 256 + threadIdx.x;
    int ngrp = O >> 3;
    int og = blockIdx.y % ngrp, b = blockIdx.y / ngrp;
    int o0 = og * 8;
    const float* xb = xin + (size_t)b * bstride + m;
    float a1[8], a2[8];
#pragma unroll
    for (int i = 0; i < 8; ++i) { a1[i] = 0.f; a2[i] = 0.f; }
#pragma unroll 2
    for (int c = 0; c < C; ++c) {
        float h = xb[(size_t)c * NPTS];
        const float* wa = Wa + c * O + o0;
        const float* wd = Wd + c * O + o0;
#pragma unroll
        for (int i = 0; i < 8; ++i) {
            a1[i] = fmaf(wa[i], h, a1[i]);
            a2[i] = fmaf(wd[i], h, a2[i]);
        }
    }
#pragma unroll
    for (int i = 0; i < 8; ++i) {
        y[((size_t)b * O + o0 + i) * NPTS + m] = a1[i];
        base[(size_t)b * base_bstride + (size_t)(o0 + i) * NPTS + m] = a2[i] + bias[o0 + i];
    }
}

// ---- feat[b,off+o,n] = lrelu( max_j y[b,o,idx[b,n,j]] + base )
__global__ __launch_bounds__(256) void gather_max_kernel(const float* __restrict__ y, int O,
                                                         const int* __restrict__ idx,
                                                         float* __restrict__ feat_slice,
                                                         long bstride) {
    __shared__ float yrow[NPTS];
    int o = blockIdx.x, b = blockIdx.y;
    const float* ysrc = y + ((size_t)b * O + o) * NPTS;
    for (int m = threadIdx.x; m < NPTS; m += 256) yrow[m] = ysrc[m];
    __syncthreads();
    float* fs = feat_slice + (size_t)b * bstride + (size_t)o * NPTS;
    const int* ib = idx + (size_t)b * NPTS * KNN;
    for (int s = 0; s < 8; ++s) {
        int n = threadIdx.x + 256 * s;
        const int* ip = ib + n * KNN;
        float mx = -INFINITY;
#pragma unroll
        for (int j = 0; j < KNN; ++j) mx = fmaxf(mx, yrow[ip[j]]);
        fs[n] = lrelu(mx + fs[n]);
    }
}

// ---- split Wf (fp32 [1024][512]) into packed bf16 hi/lo
__global__ void wf_split_kernel(const float* __restrict__ Wf,
                                unsigned* __restrict__ Wfh, unsigned* __restrict__ Wfl) {
    int t = blockIdx.x * 256 + threadIdx.x;
    if (t >= 262144) return;
    unsigned h, l;
    split2(Wf[2 * t], Wf[2 * t + 1], h, l);
    Wfh[t] = h; Wfl[t] = l;
}

// ---- final GEMM via bf16 hi/lo split MFMA, max-over-n epilogue.
// 1-D grid, XCD-aware decode: XCD j = g%8 owns batches {2j, 2j+1};
// o-tile fastest so the 8 blocks sharing a feat slice are adjacent on one XCD's L2.
__global__ __launch_bounds__(256) void final_gemm_mfma(
    const float* __restrict__ feat,
    const unsigned short* __restrict__ Wfh,
    const unsigned short* __restrict__ Wfl,
    float* __restrict__ pmax) {
    __shared__ __align__(16) unsigned short Ah[128 * GP];
    __shared__ __align__(16) unsigned short Al[128 * GP];
    __shared__ __align__(16) unsigned short Bh[128 * GP];
    __shared__ __align__(16) unsigned short Bl[128 * GP];

    int g = blockIdx.x;
    int j = g & 7, s = g >> 3;
    int b = 2 * j + (s >> 7);
    int r7 = s & 127;
    int nt = r7 >> 3, ot = r7 & 7;

    int o0 = ot * 128, n0 = nt * 128;
    int tid = threadIdx.x;
    int lane = tid & 63, w = tid >> 6;
    int wm = w & 1, wn = w >> 1;
    int l15 = lane & 15, q = lane >> 4;

    f32x4 acc[4][4];
#pragma unroll
    for (int mi = 0; mi < 4; ++mi)
#pragma unroll
        for (int ni = 0; ni < 4; ++ni) acc[mi][ni] = (f32x4)0.f;

    const float* fb = feat + (size_t)b * 512 * NPTS;
    int bn = tid & 127, kh = tid >> 7;

    for (int c0 = 0; c0 < 512; c0 += 32) {
#pragma unroll
        for (int p = 0; p < 2; ++p) {
            int e = p * 256 + tid;
            int rr = e >> 2, qq = e & 3;
            size_t go = (size_t)(o0 + rr) * 512 + c0 + qq * 8;
            *(uint4*)&Ah[rr * GP + qq * 8] = *(const uint4*)(Wfh + go);
            *(uint4*)&Al[rr * GP + qq * 8] = *(const uint4*)(Wfl + go);
        }
        {
            const float* src = fb + (size_t)(c0 + kh * 16) * NPTS + n0 + bn;
            float v[16];
#pragma unroll
            for (int jj = 0; jj < 16; ++jj) v[jj] = src[(size_t)jj * NPTS];
            unsigned hw[8], lw[8];
#pragma unroll
            for (int p = 0; p < 8; ++p) split2(v[2 * p], v[2 * p + 1], hw[p], lw[p]);
            unsigned short* bh = &Bh[bn * GP + kh * 16];
            unsigned short* bl = &Bl[bn * GP + kh * 16];
            *(uint4*)(bh)     = make_uint4(hw[0], hw[1], hw[2], hw[3]);
            *(uint4*)(bh + 8) = make_uint4(hw[4], hw[5], hw[6], hw[7]);
            *(uint4*)(bl)     = make_uint4(lw[0], lw[1], lw[2], lw[3]);
            *(uint4*)(bl + 8) = make_uint4(lw[4], lw[5], lw[6], lw[7]);
        }
        __syncthreads();

        bf16x8 bhf[4], blf[4];
#pragma unroll
        for (int ni = 0; ni < 4; ++ni) {
            int row = wn * 64 + ni * 16 + l15;
            bhf[ni] = *(const bf16x8*)&Bh[row * GP + q * 8];
            blf[ni] = *(const bf16x8*)&Bl[row * GP + q * 8];
        }
#pragma unroll
        for (int mi = 0; mi < 4; ++mi) {
            int row = wm * 64 + mi * 16 + l15;
            bf16x8 ah = *(const bf16x8*)&Ah[row * GP + q * 8];
            bf16x8 al = *(const bf16x8*)&Al[row * GP + q * 8];
#pragma unroll
            for (int ni = 0; ni < 4; ++ni) {
                acc[mi][ni] = __builtin_amdgcn_mfma_f32_16x16x32_bf16(ah, bhf[ni], acc[mi][ni], 0, 0, 0);
                acc[mi][ni] = __builtin_amdgcn_mfma_f32_16x16x32_bf16(ah, blf[ni], acc[mi][ni], 0, 0, 0);
                acc[mi][ni] = __builtin_amdgcn_mfma_f32_16x16x32_bf16(al, bhf[ni], acc[mi][ni], 0, 0, 0);
            }
        }
        __syncthreads();
    }

    int slot = nt * 2 + wn;
#pragma unroll
    for (int mi = 0; mi < 4; ++mi) {
        float m4[4];
#pragma unroll
        for (int rr = 0; rr < 4; ++rr) {
            float m = acc[mi][0][rr];
            m = fmaxf(m, acc[mi][1][rr]);
            m = fmaxf(m, acc[mi][2][rr]);
            m = fmaxf(m, acc[mi][3][rr]);
            m4[rr] = m;
        }
#pragma unroll
        for (int off = 1; off < 16; off <<= 1) {
#pragma unroll
            for (int rr = 0; rr < 4; ++rr)
                m4[rr] = fmaxf(m4[rr], __shfl_xor(m4[rr], off, 16));
        }
        if (l15 == 0) {
            int mbase = o0 + wm * 64 + mi * 16 + q * 4;
#pragma unroll
            for (int rr = 0; rr < 4; ++rr)
                pmax[((size_t)b * 1024 + mbase + rr) * 32 + slot] = m4[rr];
        }
    }
}

__global__ void final_reduce_kernel(const float* __restrict__ pmax,
                                    const float* __restrict__ bf,
                                    float* __restrict__ out) {
    int t = blockIdx.x * blockDim.x + threadIdx.x;
    if (t >= NB * 1024) return;
    const float* p = pmax + (size_t)t * 32;
    float m = p[0];
#pragma unroll
    for (int i = 1; i < 32; ++i) m = fmaxf(m, p[i]);
    out[t] = lrelu(m + bf[t & 1023]);
}

extern "C" void kernel_launch(void* const* d_in, const int* in_sizes, int n_in,
                              void* d_out, int out_size, void* d_ws, size_t ws_size,
                              hipStream_t stream) {
    const float* x  = (const float*)d_in[0];
    const float* W[4]  = {(const float*)d_in[1], (const float*)d_in[3],
                          (const float*)d_in[5], (const float*)d_in[7]};
    const float* bb[4] = {(const float*)d_in[2], (const float*)d_in[4],
                          (const float*)d_in[6], (const float*)d_in[8]};
    const float* Wf = (const float*)d_in[9];
    const float* bf = (const float*)d_in[10];
    float* out = (float*)d_out;

    float* ws   = (float*)d_ws;
    float* h0   = ws;                       // B*3*N      = 98304
    float* sq   = h0 + 98304;               // B*N        = 32768
    int*   idx  = (int*)(sq + 32768);       // B*N*20     = 655360
    float* y    = (float*)(idx + 655360);   // B*256*N    = 8388608 (multi-use)
    float* feat = y + 8388608;              // B*512*N    = 16777216
    float* Wa   = feat + 16777216 + 262144; // 128*256    = 32768
    float* Wd   = Wa + 32768;               // 128*256    = 32768

    // carved out of the y region (dead at the relevant times):
    unsigned short* xh = (unsigned short*)y;         // 16*2048*128 ushorts (8 MB max)
    unsigned short* xl = xh + (size_t)16 * 2048 * 128;
    unsigned* Wfh = (unsigned*)y;                    // after layer loop
    unsigned* Wfl = (unsigned*)(y + 262144);
    float*    pmax = y + 524288;                     // 16*1024*32 floats

    transpose_kernel<<<128, 256, 0, stream>>>(x, h0);

    const int  Cs[4]   = {3, 64, 64, 128};
    const int  Os[4]   = {64, 64, 128, 256};
    const int  offs[4] = {0, 64, 128, 256};

    for (int l = 0; l < 4; ++l) {
        const float* in = (l == 0) ? h0 : feat + (size_t)offs[l - 1] * NPTS;
        long bstr = (l == 0) ? (long)3 * NPTS : (long)512 * NPTS;
        int C = Cs[l], O = Os[l];
        int CP = (l == 0) ? 32 : C;

        xsplit_kernel<<<128, 256, 0, stream>>>(in, bstr, C, CP, xh, xl, sq);

        size_t smem = (size_t)(2 * 16 * (CP + 8) + 2 * 128 * GP) * 2 + (size_t)16 * 2050 * 4;
        dim3 kg(128, NB);
        if (CP == 32)      knn_fused<32> <<<kg, 256, smem, stream>>>(xh, xl, sq, idx);
        else if (CP == 64) knn_fused<64> <<<kg, 256, smem, stream>>>(xh, xl, sq, idx);
        else               knn_fused<128><<<kg, 256, smem, stream>>>(xh, xl, sq, idx);

        prep_w_kernel<<<(C * O + 255) / 256, 256, 0, stream>>>(W[l], C, O, Wa, Wd);

        float* fslice = feat + (size_t)offs[l] * NPTS;
        edge_mm_kernel<<<dim3(NPTS / 256, NB * (O >> 3)), 256, 0, stream>>>(
            in, bstr, C, O, Wa, Wd, bb[l], y, fslice, (long)512 * NPTS);

        gather_max_kernel<<<dim3(O, NB), 256, 0, stream>>>(y, O, idx, fslice, (long)512 * NPTS);
    }

    wf_split_kernel<<<1024, 256, 0, stream>>>(Wf, Wfh, Wfl);
    final_gemm_mfma<<<2048, 256, 0, stream>>>(
        feat, (const unsigned short*)Wfh, (const unsigned short*)Wfl, pmax);
    final_reduce_kernel<<<64, 256, 0, stream>>>(pmax, bf, out);
}

// Round 5
// 1839.585 us; speedup vs baseline: 2.2666x; 2.2666x over previous
//
#include <hip/hip_runtime.h>
#include <hip/hip_bf16.h>
#include <math.h>

#define NPTS 2048
#define NB 16
#define KNN 20
#define GP 40   // LDS pitch (bf16) for final-GEMM staging buffers

typedef __attribute__((ext_vector_type(8))) short bf16x8;
typedef __attribute__((ext_vector_type(4))) float f32x4;

__device__ __forceinline__ float lrelu(float v) { return fmaxf(v, 0.2f * v); }

// split two floats into packed bf16 hi pair + packed bf16 lo (residual) pair
__device__ __forceinline__ void split2(float a, float b, unsigned& hp, unsigned& lp) {
    float2 f2; f2.x = a; f2.y = b;
    __hip_bfloat162 h2 = __float22bfloat162_rn(f2);
    unsigned hb; __builtin_memcpy(&hb, &h2, 4);
    float la = a - __uint_as_float(hb << 16);
    float lb = b - __uint_as_float(hb & 0xFFFF0000u);
    float2 l2; l2.x = la; l2.y = lb;
    __hip_bfloat162 k2 = __float22bfloat162_rn(l2);
    unsigned lb2; __builtin_memcpy(&lb2, &k2, 4);
    hp = hb; lp = lb2;
}

// ---- transpose x [B,N,3] -> h0 [B,3,N]
__global__ void transpose_kernel(const float* __restrict__ x, float* __restrict__ h0) {
    int t = blockIdx.x * blockDim.x + threadIdx.x;
    if (t >= NB * NPTS) return;
    int b = t / NPTS, n = t % NPTS;
    const float* src = x + (size_t)t * 3;
    float* dst = h0 + (size_t)b * 3 * NPTS + n;
    dst[0]        = src[0];
    dst[NPTS]     = src[1];
    dst[2 * NPTS] = src[2];
}

// ---- split layer input [b][c][m] fp32 -> xh/xl [b][m][CP] bf16 (transposed), + sq
__global__ __launch_bounds__(256) void xsplit_kernel(const float* __restrict__ in, long bstride,
                                                     int C, int CP,
                                                     unsigned short* __restrict__ xh,
                                                     unsigned short* __restrict__ xl,
                                                     float* __restrict__ sq) {
    int t = blockIdx.x * 256 + threadIdx.x;      // b*N + m
    int b = t >> 11;
    int m = t & 2047;
    const float* p = in + (size_t)b * bstride + m;
    unsigned short* ph = xh + (size_t)t * CP;
    unsigned short* pl = xl + (size_t)t * CP;
    float s = 0.f;
    for (int c0 = 0; c0 < CP; c0 += 8) {
        float v[8];
        unsigned hw[4], lw[4];
#pragma unroll
        for (int j = 0; j < 8; ++j) {
            int c = c0 + j;
            v[j] = (c < C) ? p[(size_t)c * NPTS] : 0.f;
            s = fmaf(v[j], v[j], s);
        }
#pragma unroll
        for (int pp = 0; pp < 4; ++pp) split2(v[2 * pp], v[2 * pp + 1], hw[pp], lw[pp]);
        *(uint4*)(ph + c0) = make_uint4(hw[0], hw[1], hw[2], hw[3]);
        *(uint4*)(pl + c0) = make_uint4(lw[0], lw[1], lw[2], lw[3]);
    }
    sq[t] = s;
}

// ---- fused kNN v2: block = 16 waves, 16 query rows (one wave per row for select).
// MFMA fragments loaded directly from global (pre-transposed bf16 hi/lo). LDS only
// holds the 16x2050 fp32 score strip. Select = ballot bisection for exact top-20.
template<int CP>
__global__ __launch_bounds__(1024, 4) void knn_fused2(const unsigned short* __restrict__ xh,
                                                      const unsigned short* __restrict__ xl,
                                                      const float* __restrict__ sq,
                                                      int* __restrict__ idx) {
    extern __shared__ __align__(16) float scores[];   // [16][2050]
    constexpr int KS = CP / 32;

    int g = blockIdx.x;
    int j8 = g & 7, s = g >> 3;          // XCD j8 owns batches 2*j8, 2*j8+1
    int b = 2 * j8 + (s & 1);
    int nt = s >> 1;                     // 0..127
    int n0 = nt * 16;

    int tid = threadIdx.x;
    int w = tid >> 6, lane = tid & 63;
    int l15 = lane & 15, q = lane >> 4;

    const unsigned short* xhb = xh + (size_t)b * NPTS * CP;
    const unsigned short* xlb = xl + (size_t)b * NPTS * CP;

    // A fragments (query rows n0..n0+15): A[m=l15][k=q*8+jj]
    bf16x8 ah[KS], al[KS];
#pragma unroll
    for (int ks = 0; ks < KS; ++ks) {
        ah[ks] = *(const bf16x8*)&xhb[(size_t)(n0 + l15) * CP + ks * 32 + q * 8];
        al[ks] = *(const bf16x8*)&xlb[(size_t)(n0 + l15) * CP + ks * 32 + q * 8];
    }

    // compute: wave w covers m in [w*128, w*128+128)
    int mbase = w * 128;
#pragma unroll
    for (int c16 = 0; c16 < 8; ++c16) {
        int m0 = mbase + c16 * 16;
        f32x4 acc = (f32x4)0.f;
#pragma unroll
        for (int ks = 0; ks < KS; ++ks) {
            bf16x8 bh = *(const bf16x8*)&xhb[(size_t)(m0 + l15) * CP + ks * 32 + q * 8];
            bf16x8 bl = *(const bf16x8*)&xlb[(size_t)(m0 + l15) * CP + ks * 32 + q * 8];
            acc = __builtin_amdgcn_mfma_f32_16x16x32_bf16(ah[ks], bh, acc, 0, 0, 0);
            acc = __builtin_amdgcn_mfma_f32_16x16x32_bf16(ah[ks], bl, acc, 0, 0, 0);
            acc = __builtin_amdgcn_mfma_f32_16x16x32_bf16(al[ks], bh, acc, 0, 0, 0);
        }
        float sv = sq[b * NPTS + m0 + l15];
#pragma unroll
        for (int r = 0; r < 4; ++r)
            scores[(q * 4 + r) * 2050 + m0 + l15] = 2.f * acc[r] - sv;
    }
    __syncthreads();

    // ---- select: wave w owns query row w. keys = sortable-uint of scores.
    unsigned key[32];
#pragma unroll
    for (int u = 0; u < 32; ++u) {
        unsigned bits = __float_as_uint(scores[w * 2050 + lane + 64 * u]);
        key[u] = (bits & 0x80000000u) ? ~bits : (bits | 0x80000000u);
    }

    // bisection: largest t with count(key >= t) >= 20  ->  t = 20th-largest key
    unsigned t = 0;
    for (int bit = 31; bit >= 0; --bit) {
        unsigned cand = t | (1u << bit);
        int cnt = 0;
#pragma unroll
        for (int u = 0; u < 32; ++u)
            cnt += __popcll(__ballot(key[u] >= cand));
        if (cnt >= KNN) t = cand;
    }

    int* out = idx + ((size_t)b * NPTS + n0 + w) * KNN;
    unsigned long long below = (lane == 63) ? 0x7FFFFFFFFFFFFFFFull
                                            : ((1ull << lane) - 1);
    int base = 0;
    // emit strictly-greater (count < 20 guaranteed)
#pragma unroll
    for (int u = 0; u < 32; ++u) {
        unsigned long long mk = __ballot(key[u] > t);
        if (key[u] > t) out[base + __popcll(mk & below)] = lane + 64 * u;
        base += __popcll(mk);
    }
    // emit ties == t, lowest m index first (u ascending, lane-prefix ascending)
#pragma unroll
    for (int u = 0; u < 32; ++u) {
        if (base >= KNN) break;
        unsigned long long mk = __ballot(key[u] == t);
        int p = base + __popcll(mk & below);
        if ((key[u] == t) && p < KNN) out[p] = lane + 64 * u;
        base += __popcll(mk);
    }
}

// ---- Wa[c][o] = W[o][c]; Wd[c][o] = W[o][C+c] - W[o][c]
__global__ void prep_w_kernel(const float* __restrict__ W, int C, int O,
                              float* __restrict__ Wa, float* __restrict__ Wd) {
    int t = blockIdx.x * blockDim.x + threadIdx.x;
    if (t >= C * O) return;
    int c = t / O, o = t % O;
    float a = W[o * 2 * C + c];
    float d = W[o * 2 * C + C + c] - a;
    Wa[c * O + o] = a;
    Wd[c * O + o] = d;
}

// ---- y[b,o,m] = Wa@x_m ; base[b,off+o,n] = Wd@x_n + bias
__global__ __launch_bounds__(256) void edge_mm_kernel(const float* __restrict__ xin, long bstride,
                                                      int C, int O,
                                                      const float* __restrict__ Wa,
                                                      const float* __restrict__ Wd,
                                                      const float* __restrict__ bias,
                                                      float* __restrict__ y,
                                                      float* __restrict__ base, long base_bstride) {
    int m = blockIdx.x * 256 + threadIdx.x;
    int ngrp = O >> 3;
    int og = blockIdx.y % ngrp, b = blockIdx.y / ngrp;
    int o0 = og * 8;
    const float* xb = xin + (size_t)b * bstride + m;
    float a1[8], a2[8];
#pragma unroll
    for (int i = 0; i < 8; ++i) { a1[i] = 0.f; a2[i] = 0.f; }
#pragma unroll 2
    for (int c = 0; c < C; ++c) {
        float h = xb[(size_t)c * NPTS];
        const float* wa = Wa + c * O + o0;
        const float* wd = Wd + c * O + o0;
#pragma unroll
        for (int i = 0; i < 8; ++i) {
            a1[i] = fmaf(wa[i], h, a1[i]);
            a2[i] = fmaf(wd[i], h, a2[i]);
        }
    }
#pragma unroll
    for (int i = 0; i < 8; ++i) {
        y[((size_t)b * O + o0 + i) * NPTS + m] = a1[i];
        base[(size_t)b * base_bstride + (size_t)(o0 + i) * NPTS + m] = a2[i] + bias[o0 + i];
    }
}

// ---- feat[b,off+o,n] = lrelu( max_j y[b,o,idx[b,n,j]] + base )
__global__ __launch_bounds__(256) void gather_max_kernel(const float* __restrict__ y, int O,
                                                         const int* __restrict__ idx,
                                                         float* __restrict__ feat_slice,
                                                         long bstride) {
    __shared__ float yrow[NPTS];
    int o = blockIdx.x, b = blockIdx.y;
    const float* ysrc = y + ((size_t)b * O + o) * NPTS;
    for (int m = threadIdx.x; m < NPTS; m += 256) yrow[m] = ysrc[m];
    __syncthreads();
    float* fs = feat_slice + (size_t)b * bstride + (size_t)o * NPTS;
    const int* ib = idx + (size_t)b * NPTS * KNN;
    for (int s = 0; s < 8; ++s) {
        int n = threadIdx.x + 256 * s;
        const int* ip = ib + n * KNN;
        float mx = -INFINITY;
#pragma unroll
        for (int j = 0; j < KNN; ++j) mx = fmaxf(mx, yrow[ip[j]]);
        fs[n] = lrelu(mx + fs[n]);
    }
}

// ---- split Wf (fp32 [1024][512]) into packed bf16 hi/lo
__global__ void wf_split_kernel(const float* __restrict__ Wf,
                                unsigned* __restrict__ Wfh, unsigned* __restrict__ Wfl) {
    int t = blockIdx.x * 256 + threadIdx.x;
    if (t >= 262144) return;
    unsigned h, l;
    split2(Wf[2 * t], Wf[2 * t + 1], h, l);
    Wfh[t] = h; Wfl[t] = l;
}

// ---- final GEMM via bf16 hi/lo split MFMA, max-over-n epilogue, XCD-aware decode
__global__ __launch_bounds__(256) void final_gemm_mfma(
    const float* __restrict__ feat,
    const unsigned short* __restrict__ Wfh,
    const unsigned short* __restrict__ Wfl,
    float* __restrict__ pmax) {
    __shared__ __align__(16) unsigned short Ah[128 * GP];
    __shared__ __align__(16) unsigned short Al[128 * GP];
    __shared__ __align__(16) unsigned short Bh[128 * GP];
    __shared__ __align__(16) unsigned short Bl[128 * GP];

    int g = blockIdx.x;
    int j = g & 7, s = g >> 3;
    int b = 2 * j + (s >> 7);
    int r7 = s & 127;
    int nt = r7 >> 3, ot = r7 & 7;

    int o0 = ot * 128, n0 = nt * 128;
    int tid = threadIdx.x;
    int lane = tid & 63, w = tid >> 6;
    int wm = w & 1, wn = w >> 1;
    int l15 = lane & 15, q = lane >> 4;

    f32x4 acc[4][4];
#pragma unroll
    for (int mi = 0; mi < 4; ++mi)
#pragma unroll
        for (int ni = 0; ni < 4; ++ni) acc[mi][ni] = (f32x4)0.f;

    const float* fb = feat + (size_t)b * 512 * NPTS;
    int bn = tid & 127, kh = tid >> 7;

    for (int c0 = 0; c0 < 512; c0 += 32) {
#pragma unroll
        for (int p = 0; p < 2; ++p) {
            int e = p * 256 + tid;
            int rr = e >> 2, qq = e & 3;
            size_t go = (size_t)(o0 + rr) * 512 + c0 + qq * 8;
            *(uint4*)&Ah[rr * GP + qq * 8] = *(const uint4*)(Wfh + go);
            *(uint4*)&Al[rr * GP + qq * 8] = *(const uint4*)(Wfl + go);
        }
        {
            const float* src = fb + (size_t)(c0 + kh * 16) * NPTS + n0 + bn;
            float v[16];
#pragma unroll
            for (int jj = 0; jj < 16; ++jj) v[jj] = src[(size_t)jj * NPTS];
            unsigned hw[8], lw[8];
#pragma unroll
            for (int p = 0; p < 8; ++p) split2(v[2 * p], v[2 * p + 1], hw[p], lw[p]);
            unsigned short* bh = &Bh[bn * GP + kh * 16];
            unsigned short* bl = &Bl[bn * GP + kh * 16];
            *(uint4*)(bh)     = make_uint4(hw[0], hw[1], hw[2], hw[3]);
            *(uint4*)(bh + 8) = make_uint4(hw[4], hw[5], hw[6], hw[7]);
            *(uint4*)(bl)     = make_uint4(lw[0], lw[1], lw[2], lw[3]);
            *(uint4*)(bl + 8) = make_uint4(lw[4], lw[5], lw[6], lw[7]);
        }
        __syncthreads();

        bf16x8 bhf[4], blf[4];
#pragma unroll
        for (int ni = 0; ni < 4; ++ni) {
            int row = wn * 64 + ni * 16 + l15;
            bhf[ni] = *(const bf16x8*)&Bh[row * GP + q * 8];
            blf[ni] = *(const bf16x8*)&Bl[row * GP + q * 8];
        }
#pragma unroll
        for (int mi = 0; mi < 4; ++mi) {
            int row = wm * 64 + mi * 16 + l15;
            bf16x8 ah = *(const bf16x8*)&Ah[row * GP + q * 8];
            bf16x8 al = *(const bf16x8*)&Al[row * GP + q * 8];
#pragma unroll
            for (int ni = 0; ni < 4; ++ni) {
                acc[mi][ni] = __builtin_amdgcn_mfma_f32_16x16x32_bf16(ah, bhf[ni], acc[mi][ni], 0, 0, 0);
                acc[mi][ni] = __builtin_amdgcn_mfma_f32_16x16x32_bf16(ah, blf[ni], acc[mi][ni], 0, 0, 0);
                acc[mi][ni] = __builtin_amdgcn_mfma_f32_16x16x32_bf16(al, bhf[ni], acc[mi][ni], 0, 0, 0);
            }
        }
        __syncthreads();
    }

    int slot = nt * 2 + wn;
#pragma unroll
    for (int mi = 0; mi < 4; ++mi) {
        float m4[4];
#pragma unroll
        for (int rr = 0; rr < 4; ++rr) {
            float m = acc[mi][0][rr];
            m = fmaxf(m, acc[mi][1][rr]);
            m = fmaxf(m, acc[mi][2][rr]);
            m = fmaxf(m, acc[mi][3][rr]);
            m4[rr] = m;
        }
#pragma unroll
        for (int off = 1; off < 16; off <<= 1) {
#pragma unroll
            for (int rr = 0; rr < 4; ++rr)
                m4[rr] = fmaxf(m4[rr], __shfl_xor(m4[rr], off, 16));
        }
        if (l15 == 0) {
            int mbase = o0 + wm * 64 + mi * 16 + q * 4;
#pragma unroll
            for (int rr = 0; rr < 4; ++rr)
                pmax[((size_t)b * 1024 + mbase + rr) * 32 + slot] = m4[rr];
        }
    }
}

__global__ void final_reduce_kernel(const float* __restrict__ pmax,
                                    const float* __restrict__ bf,
                                    float* __restrict__ out) {
    int t = blockIdx.x * blockDim.x + threadIdx.x;
    if (t >= NB * 1024) return;
    const float* p = pmax + (size_t)t * 32;
    float m = p[0];
#pragma unroll
    for (int i = 1; i < 32; ++i) m = fmaxf(m, p[i]);
    out[t] = lrelu(m + bf[t & 1023]);
}

extern "C" void kernel_launch(void* const* d_in, const int* in_sizes, int n_in,
                              void* d_out, int out_size, void* d_ws, size_t ws_size,
                              hipStream_t stream) {
    const float* x  = (const float*)d_in[0];
    const float* W[4]  = {(const float*)d_in[1], (const float*)d_in[3],
                          (const float*)d_in[5], (const float*)d_in[7]};
    const float* bb[4] = {(const float*)d_in[2], (const float*)d_in[4],
                          (const float*)d_in[6], (const float*)d_in[8]};
    const float* Wf = (const float*)d_in[9];
    const float* bf = (const float*)d_in[10];
    float* out = (float*)d_out;

    float* ws   = (float*)d_ws;
    float* h0   = ws;                       // B*3*N      = 98304
    float* sq   = h0 + 98304;               // B*N        = 32768
    int*   idx  = (int*)(sq + 32768);       // B*N*20     = 655360
    float* y    = (float*)(idx + 655360);   // B*256*N    = 8388608 (multi-use)
    float* feat = y + 8388608;              // B*512*N    = 16777216
    float* Wa   = feat + 16777216 + 262144; // 128*256    = 32768
    float* Wd   = Wa + 32768;               // 128*256    = 32768

    // overlays in the y region (dead at the relevant times):
    unsigned short* xh = (unsigned short*)y;         // 16*2048*CP ushorts (<=8.4 MB)
    unsigned short* xl = xh + (size_t)16 * 2048 * 128;
    unsigned* Wfh = (unsigned*)y;                    // after layer loop
    unsigned* Wfl = (unsigned*)(y + 262144);
    float*    pmax = y + 524288;                     // 16*1024*32 floats

    transpose_kernel<<<128, 256, 0, stream>>>(x, h0);

    const int  Cs[4]   = {3, 64, 64, 128};
    const int  Os[4]   = {64, 64, 128, 256};
    const int  offs[4] = {0, 64, 128, 256};

    for (int l = 0; l < 4; ++l) {
        const float* in = (l == 0) ? h0 : feat + (size_t)offs[l - 1] * NPTS;
        long bstr = (l == 0) ? (long)3 * NPTS : (long)512 * NPTS;
        int C = Cs[l], O = Os[l];
        int CP = (l == 0) ? 32 : C;

        xsplit_kernel<<<128, 256, 0, stream>>>(in, bstr, C, CP, xh, xl, sq);

        size_t smem = (size_t)16 * 2050 * 4;   // 131200 B
        if (CP == 32)      knn_fused2<32> <<<2048, 1024, smem, stream>>>(xh, xl, sq, idx);
        else if (CP == 64) knn_fused2<64> <<<2048, 1024, smem, stream>>>(xh, xl, sq, idx);
        else               knn_fused2<128><<<2048, 1024, smem, stream>>>(xh, xl, sq, idx);

        prep_w_kernel<<<(C * O + 255) / 256, 256, 0, stream>>>(W[l], C, O, Wa, Wd);

        float* fslice = feat + (size_t)offs[l] * NPTS;
        edge_mm_kernel<<<dim3(NPTS / 256, NB * (O >> 3)), 256, 0, stream>>>(
            in, bstr, C, O, Wa, Wd, bb[l], y, fslice, (long)512 * NPTS);

        gather_max_kernel<<<dim3(O, NB), 256, 0, stream>>>(y, O, idx, fslice, (long)512 * NPTS);
    }

    wf_split_kernel<<<1024, 256, 0, stream>>>(Wf, Wfh, Wfl);
    final_gemm_mfma<<<2048, 256, 0, stream>>>(
        feat, (const unsigned short*)Wfh, (const unsigned short*)Wfl, pmax);
    final_reduce_kernel<<<64, 256, 0, stream>>>(pmax, bf, out);
}

// Round 6
// 1832.690 us; speedup vs baseline: 2.2752x; 1.0038x over previous
//
#include <hip/hip_runtime.h>
#include <hip/hip_bf16.h>
#include <math.h>

#define NPTS 2048
#define NB 16
#define KNN 20
#define GP 40   // LDS pitch (bf16) for final-GEMM staging buffers

typedef __attribute__((ext_vector_type(8))) short bf16x8;
typedef __attribute__((ext_vector_type(4))) float f32x4;

__device__ __forceinline__ float lrelu(float v) { return fmaxf(v, 0.2f * v); }

// split two floats into packed bf16 hi pair + packed bf16 lo (residual) pair
__device__ __forceinline__ void split2(float a, float b, unsigned& hp, unsigned& lp) {
    float2 f2; f2.x = a; f2.y = b;
    __hip_bfloat162 h2 = __float22bfloat162_rn(f2);
    unsigned hb; __builtin_memcpy(&hb, &h2, 4);
    float la = a - __uint_as_float(hb << 16);
    float lb = b - __uint_as_float(hb & 0xFFFF0000u);
    float2 l2; l2.x = la; l2.y = lb;
    __hip_bfloat162 k2 = __float22bfloat162_rn(l2);
    unsigned lb2; __builtin_memcpy(&lb2, &k2, 4);
    hp = hb; lp = lb2;
}

// ---- transpose x [B,N,3] -> h0 [B,3,N]
__global__ void transpose_kernel(const float* __restrict__ x, float* __restrict__ h0) {
    int t = blockIdx.x * blockDim.x + threadIdx.x;
    if (t >= NB * NPTS) return;
    int b = t / NPTS, n = t % NPTS;
    const float* src = x + (size_t)t * 3;
    float* dst = h0 + (size_t)b * 3 * NPTS + n;
    dst[0]        = src[0];
    dst[NPTS]     = src[1];
    dst[2 * NPTS] = src[2];
}

// ---- split layer input [b][c][m] fp32 -> xh/xl [b][m][CP] bf16 (transposed), + sq
__global__ __launch_bounds__(256) void xsplit_kernel(const float* __restrict__ in, long bstride,
                                                     int C, int CP,
                                                     unsigned short* __restrict__ xh,
                                                     unsigned short* __restrict__ xl,
                                                     float* __restrict__ sq) {
    int t = blockIdx.x * 256 + threadIdx.x;      // b*N + m
    int b = t >> 11;
    int m = t & 2047;
    const float* p = in + (size_t)b * bstride + m;
    unsigned short* ph = xh + (size_t)t * CP;
    unsigned short* pl = xl + (size_t)t * CP;
    float s = 0.f;
    for (int c0 = 0; c0 < CP; c0 += 8) {
        float v[8];
        unsigned hw[4], lw[4];
#pragma unroll
        for (int j = 0; j < 8; ++j) {
            int c = c0 + j;
            v[j] = (c < C) ? p[(size_t)c * NPTS] : 0.f;
            s = fmaf(v[j], v[j], s);
        }
#pragma unroll
        for (int pp = 0; pp < 4; ++pp) split2(v[2 * pp], v[2 * pp + 1], hw[pp], lw[pp]);
        *(uint4*)(ph + c0) = make_uint4(hw[0], hw[1], hw[2], hw[3]);
        *(uint4*)(pl + c0) = make_uint4(lw[0], lw[1], lw[2], lw[3]);
    }
    sq[t] = s;
}

// ---- fused kNN v2: block = 16 waves, 16 query rows (one wave per row for select).
// MFMA fragments loaded directly from global (pre-transposed bf16 hi/lo). LDS only
// holds the 16x2050 fp32 score strip. Select = ballot bisection for exact top-20.
// NOTE: __launch_bounds__(1024) only — round-5's (1024,4) capped VGPRs at 32 and
// spilled key[32]+ah/al to scratch (476 us/dispatch). 1024-thread block implies
// VGPR<=128 anyway; compiler honors that without spilling.
template<int CP>
__global__ __launch_bounds__(1024) void knn_fused2(const unsigned short* __restrict__ xh,
                                                   const unsigned short* __restrict__ xl,
                                                   const float* __restrict__ sq,
                                                   int* __restrict__ idx) {
    extern __shared__ __align__(16) float scores[];   // [16][2050]
    constexpr int KS = CP / 32;

    int g = blockIdx.x;
    int j8 = g & 7, s = g >> 3;          // XCD j8 owns batches 2*j8, 2*j8+1
    int b = 2 * j8 + (s & 1);
    int nt = s >> 1;                     // 0..127
    int n0 = nt * 16;

    int tid = threadIdx.x;
    int w = tid >> 6, lane = tid & 63;
    int l15 = lane & 15, q = lane >> 4;

    const unsigned short* xhb = xh + (size_t)b * NPTS * CP;
    const unsigned short* xlb = xl + (size_t)b * NPTS * CP;

    // A fragments (query rows n0..n0+15): A[m=l15][k=q*8+jj]
    bf16x8 ah[KS], al[KS];
#pragma unroll
    for (int ks = 0; ks < KS; ++ks) {
        ah[ks] = *(const bf16x8*)&xhb[(size_t)(n0 + l15) * CP + ks * 32 + q * 8];
        al[ks] = *(const bf16x8*)&xlb[(size_t)(n0 + l15) * CP + ks * 32 + q * 8];
    }

    // compute: wave w covers m in [w*128, w*128+128)
    int mbase = w * 128;
#pragma unroll 2
    for (int c16 = 0; c16 < 8; ++c16) {
        int m0 = mbase + c16 * 16;
        f32x4 acc = (f32x4)0.f;
#pragma unroll
        for (int ks = 0; ks < KS; ++ks) {
            bf16x8 bh = *(const bf16x8*)&xhb[(size_t)(m0 + l15) * CP + ks * 32 + q * 8];
            bf16x8 bl = *(const bf16x8*)&xlb[(size_t)(m0 + l15) * CP + ks * 32 + q * 8];
            acc = __builtin_amdgcn_mfma_f32_16x16x32_bf16(ah[ks], bh, acc, 0, 0, 0);
            acc = __builtin_amdgcn_mfma_f32_16x16x32_bf16(ah[ks], bl, acc, 0, 0, 0);
            acc = __builtin_amdgcn_mfma_f32_16x16x32_bf16(al[ks], bh, acc, 0, 0, 0);
        }
        float sv = sq[b * NPTS + m0 + l15];
#pragma unroll
        for (int r = 0; r < 4; ++r)
            scores[(q * 4 + r) * 2050 + m0 + l15] = 2.f * acc[r] - sv;
    }
    __syncthreads();

    // ---- select: wave w owns query row w. keys = sortable-uint of scores.
    unsigned key[32];
#pragma unroll
    for (int u = 0; u < 32; ++u) {
        unsigned bits = __float_as_uint(scores[w * 2050 + lane + 64 * u]);
        key[u] = (bits & 0x80000000u) ? ~bits : (bits | 0x80000000u);
    }

    // bisection: largest t with count(key >= t) >= 20  ->  t = 20th-largest key
    unsigned t = 0;
    for (int bit = 31; bit >= 0; --bit) {
        unsigned cand = t | (1u << bit);
        int cnt = 0;
#pragma unroll
        for (int u = 0; u < 32; ++u)
            cnt += __popcll(__ballot(key[u] >= cand));
        if (cnt >= KNN) t = cand;
    }

    int* out = idx + ((size_t)b * NPTS + n0 + w) * KNN;
    unsigned long long below = (lane == 63) ? 0x7FFFFFFFFFFFFFFFull
                                            : ((1ull << lane) - 1);
    int base = 0;
    // emit strictly-greater (count < 20 guaranteed)
#pragma unroll
    for (int u = 0; u < 32; ++u) {
        unsigned long long mk = __ballot(key[u] > t);
        if (key[u] > t) out[base + __popcll(mk & below)] = lane + 64 * u;
        base += __popcll(mk);
    }
    // emit ties == t, lowest m index first (u ascending, lane-prefix ascending)
#pragma unroll
    for (int u = 0; u < 32; ++u) {
        if (base >= KNN) break;
        unsigned long long mk = __ballot(key[u] == t);
        int p = base + __popcll(mk & below);
        if ((key[u] == t) && p < KNN) out[p] = lane + 64 * u;
        base += __popcll(mk);
    }
}

// ---- Wa[c][o] = W[o][c]; Wd[c][o] = W[o][C+c] - W[o][c]
__global__ void prep_w_kernel(const float* __restrict__ W, int C, int O,
                              float* __restrict__ Wa, float* __restrict__ Wd) {
    int t = blockIdx.x * blockDim.x + threadIdx.x;
    if (t >= C * O) return;
    int c = t / O, o = t % O;
    float a = W[o * 2 * C + c];
    float d = W[o * 2 * C + C + c] - a;
    Wa[c * O + o] = a;
    Wd[c * O + o] = d;
}

// ---- y[b,o,m] = Wa@x_m ; base[b,off+o,n] = Wd@x_n + bias
__global__ __launch_bounds__(256) void edge_mm_kernel(const float* __restrict__ xin, long bstride,
                                                      int C, int O,
                                                      const float* __restrict__ Wa,
                                                      const float* __restrict__ Wd,
                                                      const float* __restrict__ bias,
                                                      float* __restrict__ y,
                                                      float* __restrict__ base, long base_bstride) {
    int m = blockIdx.x * 256 + threadIdx.x;
    int ngrp = O >> 3;
    int og = blockIdx.y % ngrp, b = blockIdx.y / ngrp;
    int o0 = og * 8;
    const float* xb = xin + (size_t)b * bstride + m;
    float a1[8], a2[8];
#pragma unroll
    for (int i = 0; i < 8; ++i) { a1[i] = 0.f; a2[i] = 0.f; }
#pragma unroll 2
    for (int c = 0; c < C; ++c) {
        float h = xb[(size_t)c * NPTS];
        const float* wa = Wa + c * O + o0;
        const float* wd = Wd + c * O + o0;
#pragma unroll
        for (int i = 0; i < 8; ++i) {
            a1[i] = fmaf(wa[i], h, a1[i]);
            a2[i] = fmaf(wd[i], h, a2[i]);
        }
    }
#pragma unroll
    for (int i = 0; i < 8; ++i) {
        y[((size_t)b * O + o0 + i) * NPTS + m] = a1[i];
        base[(size_t)b * base_bstride + (size_t)(o0 + i) * NPTS + m] = a2[i] + bias[o0 + i];
    }
}

// ---- feat[b,off+o,n] = lrelu( max_j y[b,o,idx[b,n,j]] + base )
__global__ __launch_bounds__(256) void gather_max_kernel(const float* __restrict__ y, int O,
                                                         const int* __restrict__ idx,
                                                         float* __restrict__ feat_slice,
                                                         long bstride) {
    __shared__ float yrow[NPTS];
    int o = blockIdx.x, b = blockIdx.y;
    const float* ysrc = y + ((size_t)b * O + o) * NPTS;
    for (int m = threadIdx.x; m < NPTS; m += 256) yrow[m] = ysrc[m];
    __syncthreads();
    float* fs = feat_slice + (size_t)b * bstride + (size_t)o * NPTS;
    const int* ib = idx + (size_t)b * NPTS * KNN;
    for (int s = 0; s < 8; ++s) {
        int n = threadIdx.x + 256 * s;
        const int* ip = ib + n * KNN;
        float mx = -INFINITY;
#pragma unroll
        for (int j = 0; j < KNN; ++j) mx = fmaxf(mx, yrow[ip[j]]);
        fs[n] = lrelu(mx + fs[n]);
    }
}

// ---- split Wf (fp32 [1024][512]) into packed bf16 hi/lo
__global__ void wf_split_kernel(const float* __restrict__ Wf,
                                unsigned* __restrict__ Wfh, unsigned* __restrict__ Wfl) {
    int t = blockIdx.x * 256 + threadIdx.x;
    if (t >= 262144) return;
    unsigned h, l;
    split2(Wf[2 * t], Wf[2 * t + 1], h, l);
    Wfh[t] = h; Wfl[t] = l;
}

// ---- final GEMM via bf16 hi/lo split MFMA, max-over-n epilogue, XCD-aware decode
__global__ __launch_bounds__(256) void final_gemm_mfma(
    const float* __restrict__ feat,
    const unsigned short* __restrict__ Wfh,
    const unsigned short* __restrict__ Wfl,
    float* __restrict__ pmax) {
    __shared__ __align__(16) unsigned short Ah[128 * GP];
    __shared__ __align__(16) unsigned short Al[128 * GP];
    __shared__ __align__(16) unsigned short Bh[128 * GP];
    __shared__ __align__(16) unsigned short Bl[128 * GP];

    int g = blockIdx.x;
    int j = g & 7, s = g >> 3;
    int b = 2 * j + (s >> 7);
    int r7 = s & 127;
    int nt = r7 >> 3, ot = r7 & 7;

    int o0 = ot * 128, n0 = nt * 128;
    int tid = threadIdx.x;
    int lane = tid & 63, w = tid >> 6;
    int wm = w & 1, wn = w >> 1;
    int l15 = lane & 15, q = lane >> 4;

    f32x4 acc[4][4];
#pragma unroll
    for (int mi = 0; mi < 4; ++mi)
#pragma unroll
        for (int ni = 0; ni < 4; ++ni) acc[mi][ni] = (f32x4)0.f;

    const float* fb = feat + (size_t)b * 512 * NPTS;
    int bn = tid & 127, kh = tid >> 7;

    for (int c0 = 0; c0 < 512; c0 += 32) {
#pragma unroll
        for (int p = 0; p < 2; ++p) {
            int e = p * 256 + tid;
            int rr = e >> 2, qq = e & 3;
            size_t go = (size_t)(o0 + rr) * 512 + c0 + qq * 8;
            *(uint4*)&Ah[rr * GP + qq * 8] = *(const uint4*)(Wfh + go);
            *(uint4*)&Al[rr * GP + qq * 8] = *(const uint4*)(Wfl + go);
        }
        {
            const float* src = fb + (size_t)(c0 + kh * 16) * NPTS + n0 + bn;
            float v[16];
#pragma unroll
            for (int jj = 0; jj < 16; ++jj) v[jj] = src[(size_t)jj * NPTS];
            unsigned hw[8], lw[8];
#pragma unroll
            for (int p = 0; p < 8; ++p) split2(v[2 * p], v[2 * p + 1], hw[p], lw[p]);
            unsigned short* bh = &Bh[bn * GP + kh * 16];
            unsigned short* bl = &Bl[bn * GP + kh * 16];
            *(uint4*)(bh)     = make_uint4(hw[0], hw[1], hw[2], hw[3]);
            *(uint4*)(bh + 8) = make_uint4(hw[4], hw[5], hw[6], hw[7]);
            *(uint4*)(bl)     = make_uint4(lw[0], lw[1], lw[2], lw[3]);
            *(uint4*)(bl + 8) = make_uint4(lw[4], lw[5], lw[6], lw[7]);
        }
        __syncthreads();

        bf16x8 bhf[4], blf[4];
#pragma unroll
        for (int ni = 0; ni < 4; ++ni) {
            int row = wn * 64 + ni * 16 + l15;
            bhf[ni] = *(const bf16x8*)&Bh[row * GP + q * 8];
            blf[ni] = *(const bf16x8*)&Bl[row * GP + q * 8];
        }
#pragma unroll
        for (int mi = 0; mi < 4; ++mi) {
            int row = wm * 64 + mi * 16 + l15;
            bf16x8 ah = *(const bf16x8*)&Ah[row * GP + q * 8];
            bf16x8 al = *(const bf16x8*)&Al[row * GP + q * 8];
#pragma unroll
            for (int ni = 0; ni < 4; ++ni) {
                acc[mi][ni] = __builtin_amdgcn_mfma_f32_16x16x32_bf16(ah, bhf[ni], acc[mi][ni], 0, 0, 0);
                acc[mi][ni] = __builtin_amdgcn_mfma_f32_16x16x32_bf16(ah, blf[ni], acc[mi][ni], 0, 0, 0);
                acc[mi][ni] = __builtin_amdgcn_mfma_f32_16x16x32_bf16(al, bhf[ni], acc[mi][ni], 0, 0, 0);
            }
        }
        __syncthreads();
    }

    int slot = nt * 2 + wn;
#pragma unroll
    for (int mi = 0; mi < 4; ++mi) {
        float m4[4];
#pragma unroll
        for (int rr = 0; rr < 4; ++rr) {
            float m = acc[mi][0][rr];
            m = fmaxf(m, acc[mi][1][rr]);
            m = fmaxf(m, acc[mi][2][rr]);
            m = fmaxf(m, acc[mi][3][rr]);
            m4[rr] = m;
        }
#pragma unroll
        for (int off = 1; off < 16; off <<= 1) {
#pragma unroll
            for (int rr = 0; rr < 4; ++rr)
                m4[rr] = fmaxf(m4[rr], __shfl_xor(m4[rr], off, 16));
        }
        if (l15 == 0) {
            int mbase = o0 + wm * 64 + mi * 16 + q * 4;
#pragma unroll
            for (int rr = 0; rr < 4; ++rr)
                pmax[((size_t)b * 1024 + mbase + rr) * 32 + slot] = m4[rr];
        }
    }
}

__global__ void final_reduce_kernel(const float* __restrict__ pmax,
                                    const float* __restrict__ bf,
                                    float* __restrict__ out) {
    int t = blockIdx.x * blockDim.x + threadIdx.x;
    if (t >= NB * 1024) return;
    const float* p = pmax + (size_t)t * 32;
    float m = p[0];
#pragma unroll
    for (int i = 1; i < 32; ++i) m = fmaxf(m, p[i]);
    out[t] = lrelu(m + bf[t & 1023]);
}

extern "C" void kernel_launch(void* const* d_in, const int* in_sizes, int n_in,
                              void* d_out, int out_size, void* d_ws, size_t ws_size,
                              hipStream_t stream) {
    const float* x  = (const float*)d_in[0];
    const float* W[4]  = {(const float*)d_in[1], (const float*)d_in[3],
                          (const float*)d_in[5], (const float*)d_in[7]};
    const float* bb[4] = {(const float*)d_in[2], (const float*)d_in[4],
                          (const float*)d_in[6], (const float*)d_in[8]};
    const float* Wf = (const float*)d_in[9];
    const float* bf = (const float*)d_in[10];
    float* out = (float*)d_out;

    float* ws   = (float*)d_ws;
    float* h0   = ws;                       // B*3*N      = 98304
    float* sq   = h0 + 98304;               // B*N        = 32768
    int*   idx  = (int*)(sq + 32768);       // B*N*20     = 655360
    float* y    = (float*)(idx + 655360);   // B*256*N    = 8388608 (multi-use)
    float* feat = y + 8388608;              // B*512*N    = 16777216
    float* Wa   = feat + 16777216 + 262144; // 128*256    = 32768
    float* Wd   = Wa + 32768;               // 128*256    = 32768

    // overlays in the y region (dead at the relevant times):
    unsigned short* xh = (unsigned short*)y;         // 16*2048*CP ushorts (<=8.4 MB)
    unsigned short* xl = xh + (size_t)16 * 2048 * 128;
    unsigned* Wfh = (unsigned*)y;                    // after layer loop
    unsigned* Wfl = (unsigned*)(y + 262144);
    float*    pmax = y + 524288;                     // 16*1024*32 floats

    transpose_kernel<<<128, 256, 0, stream>>>(x, h0);

    const int  Cs[4]   = {3, 64, 64, 128};
    const int  Os[4]   = {64, 64, 128, 256};
    const int  offs[4] = {0, 64, 128, 256};

    for (int l = 0; l < 4; ++l) {
        const float* in = (l == 0) ? h0 : feat + (size_t)offs[l - 1] * NPTS;
        long bstr = (l == 0) ? (long)3 * NPTS : (long)512 * NPTS;
        int C = Cs[l], O = Os[l];
        int CP = (l == 0) ? 32 : C;

        xsplit_kernel<<<128, 256, 0, stream>>>(in, bstr, C, CP, xh, xl, sq);

        size_t smem = (size_t)16 * 2050 * 4;   // 131200 B
        if (CP == 32)      knn_fused2<32> <<<2048, 1024, smem, stream>>>(xh, xl, sq, idx);
        else if (CP == 64) knn_fused2<64> <<<2048, 1024, smem, stream>>>(xh, xl, sq, idx);
        else               knn_fused2<128><<<2048, 1024, smem, stream>>>(xh, xl, sq, idx);

        prep_w_kernel<<<(C * O + 255) / 256, 256, 0, stream>>>(W[l], C, O, Wa, Wd);

        float* fslice = feat + (size_t)offs[l] * NPTS;
        edge_mm_kernel<<<dim3(NPTS / 256, NB * (O >> 3)), 256, 0, stream>>>(
            in, bstr, C, O, Wa, Wd, bb[l], y, fslice, (long)512 * NPTS);

        gather_max_kernel<<<dim3(O, NB), 256, 0, stream>>>(y, O, idx, fslice, (long)512 * NPTS);
    }

    wf_split_kernel<<<1024, 256, 0, stream>>>(Wf, Wfh, Wfl);
    final_gemm_mfma<<<2048, 256, 0, stream>>>(
        feat, (const unsigned short*)Wfh, (const unsigned short*)Wfl, pmax);
    final_reduce_kernel<<<64, 256, 0, stream>>>(pmax, bf, out);
}